// Round 10
// baseline (279.766 us; speedup 1.0000x reference)
//
#include <hip/hip_runtime.h>
#include <hip/hip_fp16.h>

// Sparse graph attention (fp32 compute, fp16 gather payloads).
// v11: DIAGNOSIS + balance. Ledger: build+gaps invariant at ~171us across
// v6/v7/v8/v10 (four structures, 10->4 dispatches) while models say 40-70.
// Hypothesis: ~60us fixed per-iteration overhead outside our kernels.
// (1) row16 split into TWO half-row dispatches (~46us each) so any build
//     kernel >46us surfaces in rocprof top-5 — the measurement that four
//     rounds of restructuring lacked.
// (2) cvt via global ticket work-stealing (977 x 64KB tiles): cvt blocks
//     start immediately, bin blocks join after drain -> true balance
//     (v10's static split couldn't).
// Everything else v10: NBIN=512 private-slice part, p2 parse+spill+bucket,
// row16 gather loop byte-identical.
// Tiers: fp16 (71MB) -> fp32 (39MB) -> direct scatter -> fused atomic.

#define HD 64
#define ED 32
#define CAP 64          // bucket slots per row
#define RPP 256         // rows per partition
#define PSHIFT 8
#define D1 15           // pass-1 LDS bin depth (slice = 16 ints = 64B line)
#define SLICE 16
#define NBIN 512        // binning blocks (lambda=8/bin, ~2K spills total)
#define SPILL_CAP 65536
#define CVT_TILE 4096   // float4s per cvt work-stealing tile (64KB)

struct h4 { __half2 a, b; };   // 4 halves, 8B

// ---------------- pass 1 (wide): bin blocks + work-stealing cvt ----------
__global__ void p1_wide_kernel(const int* __restrict__ idx, int n_edges,
                               int NP, int chunk, long long pcap,
                               int* __restrict__ part,
                               long long* __restrict__ spill,
                               int* __restrict__ spill_cnt,
                               int* __restrict__ flag,
                               int* __restrict__ cvt_tick,
                               const float* __restrict__ kf,
                               const float* __restrict__ vf,
                               const float* __restrict__ ef,
                               __half* __restrict__ k16,
                               __half* __restrict__ v16,
                               __half* __restrict__ e16,
                               long long nk4, long long ne4, int ntiles) {
    extern __shared__ int sm[];          // [NP] cnt, [NP*D1] bins
    __shared__ int tk;
    int tid = threadIdx.x;

    if (blockIdx.x < NBIN) {
        // ---- bin role ----
        int* cnt  = sm;
        int* bins = sm + NP;

        for (int i = tid; i < NP; i += 256) cnt[i] = 0;
        __syncthreads();

        int e0 = blockIdx.x * chunk;
        int n  = n_edges - e0; if (n > chunk) n = chunk; if (n < 0) n = 0;

        for (int i = tid; i < n; i += 256) {
            int e = e0 + i;
            int r = idx[e];
            int c = idx[n_edges + e];
            int p = r >> PSHIFT;
            int w = ((r & (RPP - 1)) << 17) | c;
            int pos = atomicAdd(&cnt[p], 1);         // LDS atomic only
            if (pos < D1) {
                bins[p * D1 + pos] = w;
            } else {                                 // statistical overflow
                int s = atomicAdd(spill_cnt, 1);
                if (s < SPILL_CAP) spill[s] = ((long long)r << 32) | (unsigned)c;
                else *flag = 1;
            }
        }
        __syncthreads();

        // drain: 16-lane group per slice; aligned 64B line store per slice.
        int g16 = tid >> 4;
        int sl  = tid & 15;
        for (int p = g16; p < NP; p += 16) {
            int m = cnt[p]; if (m > D1) m = D1;
            long long base = (long long)p * pcap
                           + (long long)blockIdx.x * SLICE;
            int val = (sl == 0) ? m
                    : (sl <= m) ? bins[p * D1 + sl - 1] : 0;
            part[base + sl] = val;
        }
        __syncthreads();
    }

    // ---- cvt: work-stealing over 64KB tiles (all blocks participate) ----
    if (k16 == nullptr) return;
    for (;;) {
        if (tid == 0) tk = atomicAdd(cvt_tick, 1);
        __syncthreads();
        int t = tk;
        __syncthreads();
        if (t >= ntiles) break;
        long long u0 = (long long)t * CVT_TILE;
        long long total = 2 * nk4 + ne4;
        for (int i = tid; i < CVT_TILE; i += 256) {
            long long u = u0 + i;
            if (u >= total) break;
            float4 f;
            h4 h;
            if (u < nk4) {
                f = ((const float4*)kf)[u];
                h.a = __floats2half2_rn(f.x, f.y);
                h.b = __floats2half2_rn(f.z, f.w);
                ((h4*)k16)[u] = h;
            } else if (u < 2 * nk4) {
                long long w = u - nk4;
                f = ((const float4*)vf)[w];
                h.a = __floats2half2_rn(f.x, f.y);
                h.b = __floats2half2_rn(f.z, f.w);
                ((h4*)v16)[w] = h;
            } else {
                long long w = u - 2 * nk4;
                f = ((const float4*)ef)[w];
                h.a = __floats2half2_rn(f.x, f.y);
                h.b = __floats2half2_rn(f.z, f.w);
                ((h4*)e16)[w] = h;
            }
        }
    }
}

// ---------------- pass 2: slice parse + spill merge + bucket fill --------
__global__ void p2_bucket_kernel(const int* __restrict__ part,
                                 const long long* __restrict__ spill,
                                 const int* __restrict__ spill_cnt,
                                 const int* __restrict__ flag,
                                 const int* __restrict__ idx, int n_edges,
                                 int* __restrict__ count,
                                 int* __restrict__ bucket, int n_nodes,
                                 long long pcap) {
    __shared__ int cnt2[RPP / 2];
    __shared__ int win[(RPP / 2) * CAP];  // 32KB staged window
    int tid = threadIdx.x;
    if (tid < RPP / 2) cnt2[tid] = 0;
    __syncthreads();

    int p    = blockIdx.x >> 1;
    int half = blockIdx.x & 1;

    if (*flag == 0) {
        int g  = tid >> 4;
        int sl = tid & 15;
        const int* prow = part + (long long)p * pcap;
        for (int b = g; b < NBIN; b += 16) {
            int val = prow[b * SLICE + sl];
            int m = __shfl(val, 0, 16);        // header broadcast
            if (m > D1) m = D1;
            if (sl >= 1 && sl <= m) {
                int rl = val >> 17;
                if ((rl >> 7) == half) {
                    int rh = rl & 127;
                    int c  = val & 0x1FFFF;
                    int pos = atomicAdd(&cnt2[rh], 1);
                    if (pos < CAP) win[(rh << 6) + pos] = c;
                }
            }
        }
        // spill merge (~2K entries, L2-broadcast reads)
        int ns = *spill_cnt; if (ns > SPILL_CAP) ns = SPILL_CAP;
        for (int i = tid; i < ns; i += 256) {
            long long wc = spill[i];
            int r = (int)(wc >> 32);
            if ((r >> PSHIFT) == p && (((r >> 7) & 1) == half)) {
                int rh = r & 127;
                int c  = (int)(wc & 0xFFFFFFFFLL);
                int pos = atomicAdd(&cnt2[rh], 1);
                if (pos < CAP) win[(rh << 6) + pos] = c;
            }
        }
    } else {
        // catastrophic fallback (never triggers): full edge rescan
        for (int i = tid; i < n_edges; i += 256) {
            int r = idx[i];
            if ((r >> PSHIFT) == p && (((r >> 7) & 1) == half)) {
                int rh = r & 127;
                int c  = idx[n_edges + i];
                int pos = atomicAdd(&cnt2[rh], 1);
                if (pos < CAP) win[(rh << 6) + pos] = c;
            }
        }
    }
    __syncthreads();

    int r0 = (p << PSHIFT) + (half << 7);
    int rows = n_nodes - r0;
    if (rows > RPP / 2) rows = RPP / 2;
    if (rows > 0) {
        int nint4 = rows * (CAP / 4);
        int4* dst = (int4*)(bucket + (long long)r0 * CAP);
        const int4* src = (const int4*)win;
        for (int i = tid; i < nint4; i += 256) dst[i] = src[i];
        if (tid < rows) count[r0 + tid] = cnt2[tid];
    }
}

// ---------------- fallback build: direct scatter ----------------
__global__ void bucket_scatter_kernel(const int* __restrict__ idx,
                                      int* __restrict__ count,
                                      int* __restrict__ bucket, int n_edges) {
    int t = blockIdx.x * blockDim.x + threadIdx.x;
    if (t < n_edges) {
        int r = idx[t];
        int c = idx[n_edges + t];
        int p = atomicAdd(&count[r], 1);
        if (p < CAP) bucket[(long long)r * CAP + p] = c;
    }
}

// ---------------- row kernel, fp16 gathers (row-range variant) -----------
__global__ void row16_kernel(const float* __restrict__ q,
                             const __half* __restrict__ k16,
                             const __half* __restrict__ v16,
                             const float* __restrict__ eigs,
                             const __half* __restrict__ e16,
                             const float* __restrict__ lambda0,
                             const int* __restrict__ counts,
                             const int* __restrict__ col,
                             const float* __restrict__ kf,
                             const float* __restrict__ vf,
                             const int* __restrict__ idx, int n_edges,
                             float* __restrict__ out, int row0, int row1) {
    long long tid = (long long)blockIdx.x * blockDim.x + threadIdx.x;
    int r = row0 + (int)(tid >> 6);
    if (r >= row1) return;
    int lane = threadIdx.x & 63;
    int sub = lane & 15;
    int grp = lane >> 4;

    int deg = counts[r];
    const float expL = __expf(lambda0[0]);

    if (deg > CAP) {
        float qs = q[(long long)r * HD + lane] * 0.125f;
        float gs = (lane < ED) ? eigs[(long long)r * ED + lane] * expL : 0.f;
        float accs = 0.f, den = 0.f;
        for (int base = 0; base < n_edges; base += 64) {
            int e = base + lane;
            int rr = (e < n_edges) ? idx[e] : -1;
            int cc = (e < n_edges) ? idx[n_edges + e] : 0;
            unsigned long long mm = __ballot(rr == r);
            while (mm) {
                int b = __ffsll(mm) - 1;
                mm &= mm - 1;
                int c = __shfl(cc, b, 64);
                float kb = kf[(long long)c * HD + lane];
                float gb = (lane < ED) ? eigs[(long long)c * ED + lane] : 0.f;
                float s = qs * kb + gs * gb;
                #pragma unroll
                for (int off = 32; off > 0; off >>= 1) s += __shfl_xor(s, off, 64);
                float e1 = fminf(__expf(s), 5.0f);
                den += e1;
                accs += e1 * vf[(long long)c * HD + lane];
            }
        }
        float inv = (den == 0.f) ? 1.f : __frcp_rn(den);
        out[(long long)r * HD + lane] = accs * inv;
        return;
    }

    long long start = (long long)r * CAP;

    float4 qa = *(const float4*)(q    + (long long)r * HD + sub * 4);
    float2 ga = *(const float2*)(eigs + (long long)r * ED + sub * 2);
    qa.x *= 0.125f; qa.y *= 0.125f; qa.z *= 0.125f; qa.w *= 0.125f;
    ga.x *= expL;   ga.y *= expL;

    float4 acc = make_float4(0.f, 0.f, 0.f, 0.f);
    float den = 0.f;

    for (int base = 0; base < deg; base += 64) {
        int m = deg - base; if (m > 64) m = 64;
        int cl = (lane < m) ? col[start + base + lane] : 0;
        for (int j = 0; j < m; j += 16) {
            int c1 = __shfl(cl, j + grp,      64);
            int c2 = __shfl(cl, j + 4 + grp,  64);
            int c3 = __shfl(cl, j + 8 + grp,  64);
            int c4 = __shfl(cl, j + 12 + grp, 64);
            h4 kb1 = *(const h4*)(k16 + (long long)c1 * HD + sub * 4);
            __half2 gh1 = *(const __half2*)(e16 + (long long)c1 * ED + sub * 2);
            h4 vv1 = *(const h4*)(v16 + (long long)c1 * HD + sub * 4);
            h4 kb2 = *(const h4*)(k16 + (long long)c2 * HD + sub * 4);
            __half2 gh2 = *(const __half2*)(e16 + (long long)c2 * ED + sub * 2);
            h4 vv2 = *(const h4*)(v16 + (long long)c2 * HD + sub * 4);
            h4 kb3 = *(const h4*)(k16 + (long long)c3 * HD + sub * 4);
            __half2 gh3 = *(const __half2*)(e16 + (long long)c3 * ED + sub * 2);
            h4 vv3 = *(const h4*)(v16 + (long long)c3 * HD + sub * 4);
            h4 kb4 = *(const h4*)(k16 + (long long)c4 * HD + sub * 4);
            __half2 gh4 = *(const __half2*)(e16 + (long long)c4 * ED + sub * 2);
            h4 vv4 = *(const h4*)(v16 + (long long)c4 * HD + sub * 4);

            float s1 = qa.x*__low2float(kb1.a) + qa.y*__high2float(kb1.a)
                     + qa.z*__low2float(kb1.b) + qa.w*__high2float(kb1.b)
                     + ga.x*__low2float(gh1)   + ga.y*__high2float(gh1);
            float s2 = qa.x*__low2float(kb2.a) + qa.y*__high2float(kb2.a)
                     + qa.z*__low2float(kb2.b) + qa.w*__high2float(kb2.b)
                     + ga.x*__low2float(gh2)   + ga.y*__high2float(gh2);
            float s3 = qa.x*__low2float(kb3.a) + qa.y*__high2float(kb3.a)
                     + qa.z*__low2float(kb3.b) + qa.w*__high2float(kb3.b)
                     + ga.x*__low2float(gh3)   + ga.y*__high2float(gh3);
            float s4 = qa.x*__low2float(kb4.a) + qa.y*__high2float(kb4.a)
                     + qa.z*__low2float(kb4.b) + qa.w*__high2float(kb4.b)
                     + ga.x*__low2float(gh4)   + ga.y*__high2float(gh4);
            #pragma unroll
            for (int off = 8; off > 0; off >>= 1) {
                s1 += __shfl_xor(s1, off, 64);
                s2 += __shfl_xor(s2, off, 64);
                s3 += __shfl_xor(s3, off, 64);
                s4 += __shfl_xor(s4, off, 64);
            }
            float e1 = fminf(__expf(s1), 5.0f);
            float e2 = fminf(__expf(s2), 5.0f);
            float e3 = fminf(__expf(s3), 5.0f);
            float e4 = fminf(__expf(s4), 5.0f);

            if (j + grp < m) {
                den += e1;
                acc.x += e1 * __low2float(vv1.a); acc.y += e1 * __high2float(vv1.a);
                acc.z += e1 * __low2float(vv1.b); acc.w += e1 * __high2float(vv1.b);
            }
            if (j + 4 + grp < m) {
                den += e2;
                acc.x += e2 * __low2float(vv2.a); acc.y += e2 * __high2float(vv2.a);
                acc.z += e2 * __low2float(vv2.b); acc.w += e2 * __high2float(vv2.b);
            }
            if (j + 8 + grp < m) {
                den += e3;
                acc.x += e3 * __low2float(vv3.a); acc.y += e3 * __high2float(vv3.a);
                acc.z += e3 * __low2float(vv3.b); acc.w += e3 * __high2float(vv3.b);
            }
            if (j + 12 + grp < m) {
                den += e4;
                acc.x += e4 * __low2float(vv4.a); acc.y += e4 * __high2float(vv4.a);
                acc.z += e4 * __low2float(vv4.b); acc.w += e4 * __high2float(vv4.b);
            }
        }
    }

    #pragma unroll
    for (int off = 16; off < 64; off <<= 1) {
        acc.x += __shfl_xor(acc.x, off, 64);
        acc.y += __shfl_xor(acc.y, off, 64);
        acc.z += __shfl_xor(acc.z, off, 64);
        acc.w += __shfl_xor(acc.w, off, 64);
        den   += __shfl_xor(den,   off, 64);
    }

    if (grp == 0) {
        float inv = (den == 0.0f) ? 1.0f : __frcp_rn(den);
        float4 o = make_float4(acc.x * inv, acc.y * inv, acc.z * inv, acc.w * inv);
        *(float4*)(out + (long long)r * HD + sub * 4) = o;
    }
}

// ---------------- row kernel, fp32 (fallback tiers) ----------------
__global__ void row_kernel(const float* __restrict__ q, const float* __restrict__ k,
                           const float* __restrict__ v, const float* __restrict__ eigs,
                           const float* __restrict__ lambda0,
                           const int* __restrict__ counts,
                           const int* __restrict__ col,
                           const int* __restrict__ idx, int n_edges,
                           float* __restrict__ out, int n_nodes) {
    long long tid = (long long)blockIdx.x * blockDim.x + threadIdx.x;
    int r = (int)(tid >> 6);
    if (r >= n_nodes) return;
    int lane = threadIdx.x & 63;
    int sub = lane & 15;
    int grp = lane >> 4;

    int deg = counts[r];
    const float expL = __expf(lambda0[0]);

    if (deg > CAP) {
        float qs = q[(long long)r * HD + lane] * 0.125f;
        float gs = (lane < ED) ? eigs[(long long)r * ED + lane] * expL : 0.f;
        float accs = 0.f, den = 0.f;
        for (int base = 0; base < n_edges; base += 64) {
            int e = base + lane;
            int rr = (e < n_edges) ? idx[e] : -1;
            int cc = (e < n_edges) ? idx[n_edges + e] : 0;
            unsigned long long mm = __ballot(rr == r);
            while (mm) {
                int b = __ffsll(mm) - 1;
                mm &= mm - 1;
                int c = __shfl(cc, b, 64);
                float kb = k[(long long)c * HD + lane];
                float gb = (lane < ED) ? eigs[(long long)c * ED + lane] : 0.f;
                float s = qs * kb + gs * gb;
                #pragma unroll
                for (int off = 32; off > 0; off >>= 1) s += __shfl_xor(s, off, 64);
                float e1 = fminf(__expf(s), 5.0f);
                den += e1;
                accs += e1 * v[(long long)c * HD + lane];
            }
        }
        float inv = (den == 0.f) ? 1.f : __frcp_rn(den);
        out[(long long)r * HD + lane] = accs * inv;
        return;
    }

    long long start = (long long)r * CAP;

    float4 qa = *(const float4*)(q    + (long long)r * HD + sub * 4);
    float2 ga = *(const float2*)(eigs + (long long)r * ED + sub * 2);
    qa.x *= 0.125f; qa.y *= 0.125f; qa.z *= 0.125f; qa.w *= 0.125f;
    ga.x *= expL;   ga.y *= expL;

    float4 acc = make_float4(0.f, 0.f, 0.f, 0.f);
    float den = 0.f;

    for (int base = 0; base < deg; base += 64) {
        int m = deg - base; if (m > 64) m = 64;
        int cl = (lane < m) ? col[start + base + lane] : 0;
        for (int j = 0; j < m; j += 8) {
            int c1 = __shfl(cl, j + grp,     64);
            int c2 = __shfl(cl, j + 4 + grp, 64);
            float4 kb1 = *(const float4*)(k    + (long long)c1 * HD + sub * 4);
            float2 gb1 = *(const float2*)(eigs + (long long)c1 * ED + sub * 2);
            float4 vv1 = *(const float4*)(v    + (long long)c1 * HD + sub * 4);
            float4 kb2 = *(const float4*)(k    + (long long)c2 * HD + sub * 4);
            float2 gb2 = *(const float2*)(eigs + (long long)c2 * ED + sub * 2);
            float4 vv2 = *(const float4*)(v    + (long long)c2 * HD + sub * 4);

            float s1 = qa.x*kb1.x + qa.y*kb1.y + qa.z*kb1.z + qa.w*kb1.w
                     + ga.x*gb1.x + ga.y*gb1.y;
            float s2 = qa.x*kb2.x + qa.y*kb2.y + qa.z*kb2.z + qa.w*kb2.w
                     + ga.x*gb2.x + ga.y*gb2.y;
            #pragma unroll
            for (int off = 8; off > 0; off >>= 1) {
                s1 += __shfl_xor(s1, off, 64);
                s2 += __shfl_xor(s2, off, 64);
            }
            float e1 = fminf(__expf(s1), 5.0f);
            float e2 = fminf(__expf(s2), 5.0f);

            if (j + grp < m) {
                den += e1;
                acc.x += e1 * vv1.x; acc.y += e1 * vv1.y;
                acc.z += e1 * vv1.z; acc.w += e1 * vv1.w;
            }
            if (j + 4 + grp < m) {
                den += e2;
                acc.x += e2 * vv2.x; acc.y += e2 * vv2.y;
                acc.z += e2 * vv2.z; acc.w += e2 * vv2.w;
            }
        }
    }

    #pragma unroll
    for (int off = 16; off < 64; off <<= 1) {
        acc.x += __shfl_xor(acc.x, off, 64);
        acc.y += __shfl_xor(acc.y, off, 64);
        acc.z += __shfl_xor(acc.z, off, 64);
        acc.w += __shfl_xor(acc.w, off, 64);
        den   += __shfl_xor(den,   off, 64);
    }

    if (grp == 0) {
        float inv = (den == 0.0f) ? 1.0f : __frcp_rn(den);
        float4 o = make_float4(acc.x * inv, acc.y * inv, acc.z * inv, acc.w * inv);
        *(float4*)(out + (long long)r * HD + sub * 4) = o;
    }
}

// ---------------- tier-3: fused atomic path ----------------
__global__ void edge_fused_kernel(const float* __restrict__ q,
                                  const float* __restrict__ k,
                                  const float* __restrict__ v,
                                  const float* __restrict__ eigs,
                                  const float* __restrict__ lambda0,
                                  const int* __restrict__ idx,
                                  float* __restrict__ denom,
                                  float* __restrict__ out, int n_edges) {
    long long gid = (long long)blockIdx.x * blockDim.x + threadIdx.x;
    int lane = threadIdx.x & 63;
    int edge = (int)(gid >> 4);
    int sub  = (int)(gid & 15);
    int valid = (edge < n_edges);
    int ec = valid ? edge : (n_edges - 1);
    int i0 = idx[ec];
    int i1 = idx[n_edges + ec];
    const float expL = __expf(lambda0[0]);
    float4 qa = *(const float4*)(q + (long long)i0 * HD + sub * 4);
    float4 kb = *(const float4*)(k + (long long)i1 * HD + sub * 4);
    float c = (qa.x*kb.x + qa.y*kb.y + qa.z*kb.z + qa.w*kb.w) * 0.125f;
    float2 ea = *(const float2*)(eigs + (long long)i0 * ED + sub * 2);
    float2 eb = *(const float2*)(eigs + (long long)i1 * ED + sub * 2);
    c += expL * (ea.x * eb.x + ea.y * eb.y);
    #pragma unroll
    for (int off = 8; off > 0; off >>= 1) c += __shfl_xor(c, off, 64);
    float e = fminf(__expf(c), 5.0f);
    if (valid && sub == 0) atomicAdd(&denom[i0], e);
    #pragma unroll
    for (int j = 0; j < 4; ++j) {
        float ej = __shfl(e,     j * 16, 64);
        int   r  = __shfl(i0,    j * 16, 64);
        int   s  = __shfl(i1,    j * 16, 64);
        int   vj = __shfl(valid, j * 16, 64);
        if (vj) {
            float vv = v[(long long)s * HD + lane];
            atomicAdd(&out[(long long)r * HD + lane], ej * vv);
        }
    }
}

__global__ void normalize_kernel(float* __restrict__ out,
                                 const float* __restrict__ denom, int n_nodes) {
    int t = blockIdx.x * blockDim.x + threadIdx.x;
    int total = n_nodes * (HD / 4);
    if (t >= total) return;
    int row = t >> 4;
    float d = denom[row];
    float inv = (d == 0.0f) ? 1.0f : __frcp_rn(d);
    float4* o4 = (float4*)out;
    float4 x = o4[t];
    x.x *= inv; x.y *= inv; x.z *= inv; x.w *= inv;
    o4[t] = x;
}

extern "C" void kernel_launch(void* const* d_in, const int* in_sizes, int n_in,
                              void* d_out, int out_size, void* d_ws, size_t ws_size,
                              hipStream_t stream) {
    const float* q       = (const float*)d_in[0];
    const float* k       = (const float*)d_in[1];
    const float* v       = (const float*)d_in[2];
    const float* eigs    = (const float*)d_in[3];
    const float* lambda0 = (const float*)d_in[4];
    const int*   idx     = (const int*)d_in[5];   // [2, E], int32

    const int n_edges = in_sizes[5] / 2;
    const int n_nodes = in_sizes[0] / HD;

    const int NP = (n_nodes + RPP - 1) / RPP;
    const int eb = (n_edges + 255) / 256;
    long long rthreads = (long long)n_nodes * 64;
    const int rb = (int)((rthreads + 255) / 256);

    size_t smbytes = (size_t)NP * (1 + D1) * sizeof(int);
    bool geom_ok = (smbytes <= 60 * 1024) && (n_nodes <= 0x1FFFF);

    size_t sp  = 16 + (size_t)SPILL_CAP * sizeof(long long);
    size_t h16 = (size_t)n_nodes * (HD + HD + ED) * sizeof(__half);
    size_t fixed = (size_t)n_nodes * sizeof(int)
                 + (size_t)n_nodes * CAP * sizeof(int);
    size_t pbytes = (size_t)NP * (size_t)NBIN * SLICE * sizeof(int);
    size_t n16 = h16 + fixed + pbytes + sp;      // ~71MB
    size_t n32 = fixed + pbytes + sp;            // ~39MB
    size_t need2 = fixed;

    long long pcap = (long long)NBIN * SLICE;
    int chunk = (n_edges + NBIN - 1) / NBIN;

    if (geom_ok && ws_size >= n16) {
        // -------- tier 1: wide build + split fp16 row kernels --------
        char* base = (char*)d_ws;
        __half* k16 = (__half*)base;                     // [N*HD]
        __half* v16 = k16 + (size_t)n_nodes * HD;        // [N*HD]
        __half* e16 = v16 + (size_t)n_nodes * HD;        // [N*ED]
        int* count  = (int*)(e16 + (size_t)n_nodes * ED);// [N]
        int* bucket = count + n_nodes;                   // [N*CAP]
        int* part   = bucket + (size_t)n_nodes * CAP;    // [NP*NBIN*SLICE]
        int* spill_cnt = part + (size_t)NP * pcap;       // [1]
        int* flag      = spill_cnt + 1;                  // [1]
        int* cvt_tick  = spill_cnt + 2;                  // [1] (+1 pad)
        size_t soff = (size_t)((char*)(spill_cnt + 4) - base);
        soff = (soff + 7) & ~(size_t)7;
        long long* spill = (long long*)(base + soff);    // [SPILL_CAP]

        hipMemsetAsync(spill_cnt, 0, 4 * sizeof(int), stream);

        long long nk4 = (long long)n_nodes * HD / 4;
        long long ne4 = (long long)n_nodes * ED / 4;
        int ntiles = (int)((2 * nk4 + ne4 + CVT_TILE - 1) / CVT_TILE);

        p1_wide_kernel<<<2 * NBIN, 256, smbytes, stream>>>(
            idx, n_edges, NP, chunk, pcap, part, spill, spill_cnt, flag,
            cvt_tick, k, v, eigs, k16, v16, e16, nk4, ne4, ntiles);
        p2_bucket_kernel<<<2 * NP, 256, 0, stream>>>(
            part, spill, spill_cnt, flag, idx, n_edges, count, bucket,
            n_nodes, pcap);
        int rh = (n_nodes + 1) / 2;
        int rb1 = (int)(((long long)rh * 64 + 255) / 256);
        int rb2 = (int)(((long long)(n_nodes - rh) * 64 + 255) / 256);
        row16_kernel<<<rb1, 256, 0, stream>>>(q, k16, v16, eigs, e16, lambda0,
                                              count, bucket, k, v, idx, n_edges,
                                              (float*)d_out, 0, rh);
        row16_kernel<<<rb2, 256, 0, stream>>>(q, k16, v16, eigs, e16, lambda0,
                                              count, bucket, k, v, idx, n_edges,
                                              (float*)d_out, rh, n_nodes);
    } else if (geom_ok && ws_size >= n32) {
        // -------- tier 1f: wide build (no cvt) + fp32 row kernel --------
        char* base = (char*)d_ws;
        int* count  = (int*)base;
        int* bucket = count + n_nodes;
        int* part   = bucket + (size_t)n_nodes * CAP;
        int* spill_cnt = part + (size_t)NP * pcap;
        int* flag      = spill_cnt + 1;
        int* cvt_tick  = spill_cnt + 2;
        size_t soff = (size_t)((char*)(spill_cnt + 4) - base);
        soff = (soff + 7) & ~(size_t)7;
        long long* spill = (long long*)(base + soff);

        hipMemsetAsync(spill_cnt, 0, 4 * sizeof(int), stream);

        p1_wide_kernel<<<2 * NBIN, 256, smbytes, stream>>>(
            idx, n_edges, NP, chunk, pcap, part, spill, spill_cnt, flag,
            cvt_tick, nullptr, nullptr, nullptr, nullptr, nullptr, nullptr,
            0, 0, 0);
        p2_bucket_kernel<<<2 * NP, 256, 0, stream>>>(
            part, spill, spill_cnt, flag, idx, n_edges, count, bucket,
            n_nodes, pcap);
        row_kernel<<<rb, 256, 0, stream>>>(q, k, v, eigs, lambda0, count, bucket,
                                           idx, n_edges, (float*)d_out, n_nodes);
    } else if (ws_size >= need2) {
        // -------- tier 2: direct scatter --------
        int* count  = (int*)d_ws;
        int* bucket = count + n_nodes;
        hipMemsetAsync(count, 0, (size_t)n_nodes * sizeof(int), stream);
        bucket_scatter_kernel<<<eb, 256, 0, stream>>>(idx, count, bucket, n_edges);
        row_kernel<<<rb, 256, 0, stream>>>(q, k, v, eigs, lambda0, count, bucket,
                                           idx, n_edges, (float*)d_out, n_nodes);
    } else {
        // -------- tier 3: fused atomic path --------
        float* denom = (float*)d_ws;   // [N]
        hipMemsetAsync(denom, 0, (size_t)n_nodes * sizeof(float), stream);
        hipMemsetAsync(d_out, 0, (size_t)out_size * sizeof(float), stream);
        long long threads = (long long)n_edges * 16;
        int grid = (int)((threads + 255) / 256);
        edge_fused_kernel<<<grid, 256, 0, stream>>>(q, k, v, eigs, lambda0, idx,
                                                    denom, (float*)d_out, n_edges);
        int n4 = n_nodes * (HD / 4);
        normalize_kernel<<<(n4 + 255) / 256, 256, 0, stream>>>((float*)d_out,
                                                               denom, n_nodes);
    }
}

// Round 11
// 244.649 us; speedup vs baseline: 1.1435x; 1.1435x over previous
//
#include <hip/hip_runtime.h>
#include <hip/hip_fp16.h>

// Sparse graph attention (fp32 compute, fp16 gather payloads).
// v12: 3 dispatches + latency-fixed p1. Round-10 measurements:
//  (a) p1_wide = 64us @ VALUBusy 4.4% / 16% BW -> latency-starved (1
//      outstanding load/thread in both bin and cvt loops). Fix: 4x unroll
//      (bin: 4 edges/thread/iter = 8 loads in flight; cvt: 4 batched
//      float4->h4 per iter).
//  (b) +1 dispatch of identical work cost +18.7us -> dispatch boundaries
//      are ~10-19us each. Fix: row16 un-split AND memset dispatch deleted:
//      per-block PRIVATE spill slices (header written unconditionally by
//      every bin block; -1 = overflow -> p2's rescan path) -> no global
//      counters -> nothing to pre-zero. Pipeline: p1 -> p2 -> row16.
// Tiers: fp16 (73MB) -> fp32 (41MB) -> direct scatter -> fused atomic.

#define HD 64
#define ED 32
#define CAP 64          // bucket slots per row
#define RPP 256         // rows per partition
#define PSHIFT 8
#define D1 15           // pass-1 LDS bin depth (slice = 16 ints = 64B line)
#define SLICE 16
#define NBIN 512        // binning blocks (lambda~8/bin)
#define SPCAP_B 512     // private spill entries per bin block (expect ~4)

struct h4 { __half2 a, b; };   // 4 halves, 8B

// ---------------- pass 1 (wide): bin blocks + cvt blocks, no atomics -----
__global__ void p1_wide_kernel(const int* __restrict__ idx, int n_edges,
                               int NP, int chunk, long long pcap,
                               int* __restrict__ part,
                               long long* __restrict__ spill,   // [NBIN*SPCAP_B]
                               int* __restrict__ sphdr,         // [NBIN]
                               const float* __restrict__ kf,
                               const float* __restrict__ vf,
                               const float* __restrict__ ef,
                               __half* __restrict__ k16,
                               __half* __restrict__ v16,
                               __half* __restrict__ e16,
                               long long nk4, long long ne4) {
    extern __shared__ int sm[];          // [NP] cnt, [NP*D1] bins
    __shared__ int spn;
    int tid = threadIdx.x;

    if (blockIdx.x >= NBIN) {
        // ---- cvt role: stream fp32 -> fp16, 4x strided unroll ----
        if (k16 == nullptr) return;
        long long gt = (long long)(blockIdx.x - NBIN) * 256 + tid;
        long long gs = (long long)NBIN * 256;
        long long t;
        t = gt;
        for (; t + 3 * gs < nk4; t += 4 * gs) {
            float4 f0 = ((const float4*)kf)[t];
            float4 f1 = ((const float4*)kf)[t + gs];
            float4 f2 = ((const float4*)kf)[t + 2 * gs];
            float4 f3 = ((const float4*)kf)[t + 3 * gs];
            h4 h0, h1, h2, h3;
            h0.a = __floats2half2_rn(f0.x, f0.y); h0.b = __floats2half2_rn(f0.z, f0.w);
            h1.a = __floats2half2_rn(f1.x, f1.y); h1.b = __floats2half2_rn(f1.z, f1.w);
            h2.a = __floats2half2_rn(f2.x, f2.y); h2.b = __floats2half2_rn(f2.z, f2.w);
            h3.a = __floats2half2_rn(f3.x, f3.y); h3.b = __floats2half2_rn(f3.z, f3.w);
            ((h4*)k16)[t] = h0;
            ((h4*)k16)[t + gs] = h1;
            ((h4*)k16)[t + 2 * gs] = h2;
            ((h4*)k16)[t + 3 * gs] = h3;
        }
        for (; t < nk4; t += gs) {
            float4 f = ((const float4*)kf)[t];
            h4 h;
            h.a = __floats2half2_rn(f.x, f.y); h.b = __floats2half2_rn(f.z, f.w);
            ((h4*)k16)[t] = h;
        }
        t = gt;
        for (; t + 3 * gs < nk4; t += 4 * gs) {
            float4 f0 = ((const float4*)vf)[t];
            float4 f1 = ((const float4*)vf)[t + gs];
            float4 f2 = ((const float4*)vf)[t + 2 * gs];
            float4 f3 = ((const float4*)vf)[t + 3 * gs];
            h4 h0, h1, h2, h3;
            h0.a = __floats2half2_rn(f0.x, f0.y); h0.b = __floats2half2_rn(f0.z, f0.w);
            h1.a = __floats2half2_rn(f1.x, f1.y); h1.b = __floats2half2_rn(f1.z, f1.w);
            h2.a = __floats2half2_rn(f2.x, f2.y); h2.b = __floats2half2_rn(f2.z, f2.w);
            h3.a = __floats2half2_rn(f3.x, f3.y); h3.b = __floats2half2_rn(f3.z, f3.w);
            ((h4*)v16)[t] = h0;
            ((h4*)v16)[t + gs] = h1;
            ((h4*)v16)[t + 2 * gs] = h2;
            ((h4*)v16)[t + 3 * gs] = h3;
        }
        for (; t < nk4; t += gs) {
            float4 f = ((const float4*)vf)[t];
            h4 h;
            h.a = __floats2half2_rn(f.x, f.y); h.b = __floats2half2_rn(f.z, f.w);
            ((h4*)v16)[t] = h;
        }
        t = gt;
        for (; t + 3 * gs < ne4; t += 4 * gs) {
            float4 f0 = ((const float4*)ef)[t];
            float4 f1 = ((const float4*)ef)[t + gs];
            float4 f2 = ((const float4*)ef)[t + 2 * gs];
            float4 f3 = ((const float4*)ef)[t + 3 * gs];
            h4 h0, h1, h2, h3;
            h0.a = __floats2half2_rn(f0.x, f0.y); h0.b = __floats2half2_rn(f0.z, f0.w);
            h1.a = __floats2half2_rn(f1.x, f1.y); h1.b = __floats2half2_rn(f1.z, f1.w);
            h2.a = __floats2half2_rn(f2.x, f2.y); h2.b = __floats2half2_rn(f2.z, f2.w);
            h3.a = __floats2half2_rn(f3.x, f3.y); h3.b = __floats2half2_rn(f3.z, f3.w);
            ((h4*)e16)[t] = h0;
            ((h4*)e16)[t + gs] = h1;
            ((h4*)e16)[t + 2 * gs] = h2;
            ((h4*)e16)[t + 3 * gs] = h3;
        }
        for (; t < ne4; t += gs) {
            float4 f = ((const float4*)ef)[t];
            h4 h;
            h.a = __floats2half2_rn(f.x, f.y); h.b = __floats2half2_rn(f.z, f.w);
            ((h4*)e16)[t] = h;
        }
        return;
    }

    // ---- bin role ----
    int* cnt  = sm;
    int* bins = sm + NP;
    long long* myspill = spill + (long long)blockIdx.x * SPCAP_B;

    if (tid == 0) spn = 0;
    for (int i = tid; i < NP; i += 256) cnt[i] = 0;
    __syncthreads();

    int e0 = blockIdx.x * chunk;
    int n  = n_edges - e0; if (n > chunk) n = chunk; if (n < 0) n = 0;

    int i = tid;
    for (; i + 768 < n; i += 1024) {
        int e  = e0 + i;
        int r0 = idx[e];
        int r1 = idx[e + 256];
        int r2 = idx[e + 512];
        int r3 = idx[e + 768];
        int c0 = idx[n_edges + e];
        int c1 = idx[n_edges + e + 256];
        int c2 = idx[n_edges + e + 512];
        int c3 = idx[n_edges + e + 768];
        #pragma unroll
        for (int u = 0; u < 4; ++u) {
            int r = (u == 0) ? r0 : (u == 1) ? r1 : (u == 2) ? r2 : r3;
            int c = (u == 0) ? c0 : (u == 1) ? c1 : (u == 2) ? c2 : c3;
            int p = r >> PSHIFT;
            int w = ((r & (RPP - 1)) << 17) | c;
            int pos = atomicAdd(&cnt[p], 1);
            if (pos < D1) {
                bins[p * D1 + pos] = w;
            } else {
                int s = atomicAdd(&spn, 1);
                if (s < SPCAP_B) myspill[s] = ((long long)r << 32) | (unsigned)c;
            }
        }
    }
    for (; i < n; i += 256) {
        int e = e0 + i;
        int r = idx[e];
        int c = idx[n_edges + e];
        int p = r >> PSHIFT;
        int w = ((r & (RPP - 1)) << 17) | c;
        int pos = atomicAdd(&cnt[p], 1);
        if (pos < D1) {
            bins[p * D1 + pos] = w;
        } else {
            int s = atomicAdd(&spn, 1);
            if (s < SPCAP_B) myspill[s] = ((long long)r << 32) | (unsigned)c;
        }
    }
    __syncthreads();

    if (tid == 0) sphdr[blockIdx.x] = (spn > SPCAP_B) ? -1 : spn;

    // drain: 16-lane group per slice; one aligned 64B line store per slice.
    int g16 = tid >> 4;
    int sl  = tid & 15;
    for (int p = g16; p < NP; p += 16) {
        int m = cnt[p]; if (m > D1) m = D1;
        long long base = (long long)p * pcap + (long long)blockIdx.x * SLICE;
        int val = (sl == 0) ? m
                : (sl <= m) ? bins[p * D1 + sl - 1] : 0;
        part[base + sl] = val;
    }
}

// ---------------- pass 2: slice parse + spill merge + bucket fill --------
__global__ void p2_bucket_kernel(const int* __restrict__ part,
                                 const long long* __restrict__ spill,
                                 const int* __restrict__ sphdr,
                                 const int* __restrict__ idx, int n_edges,
                                 int* __restrict__ count,
                                 int* __restrict__ bucket, int n_nodes,
                                 long long pcap) {
    __shared__ int cnt2[RPP / 2];
    __shared__ int win[(RPP / 2) * CAP];  // 32KB staged window
    __shared__ int cata;
    int tid = threadIdx.x;
    if (tid == 0) cata = 0;
    if (tid < RPP / 2) cnt2[tid] = 0;
    __syncthreads();

    for (int b = tid; b < NBIN; b += 256)
        if (sphdr[b] < 0) cata = 1;
    __syncthreads();

    int p    = blockIdx.x >> 1;
    int half = blockIdx.x & 1;

    if (cata == 0) {
        int g  = tid >> 4;
        int sl = tid & 15;
        const int* prow = part + (long long)p * pcap;
        for (int b = g; b < NBIN; b += 16) {
            int val = prow[b * SLICE + sl];
            int m = __shfl(val, 0, 16);        // header broadcast
            if (m > D1) m = D1;
            if (sl >= 1 && sl <= m) {
                int rl = val >> 17;
                if ((rl >> 7) == half) {
                    int rh = rl & 127;
                    int c  = val & 0x1FFFF;
                    int pos = atomicAdd(&cnt2[rh], 1);
                    if (pos < CAP) win[(rh << 6) + pos] = c;
                }
            }
        }
        // spill merge: per-thread scan of private spill slices (~4/blk)
        for (int b = tid; b < NBIN; b += 256) {
            int ns = sphdr[b];
            const long long* sp = spill + (long long)b * SPCAP_B;
            for (int i2 = 0; i2 < ns; ++i2) {
                long long wc = sp[i2];
                int r = (int)(wc >> 32);
                if ((r >> PSHIFT) == p && (((r >> 7) & 1) == half)) {
                    int rh = r & 127;
                    int c  = (int)(wc & 0xFFFFFFFFLL);
                    int pos = atomicAdd(&cnt2[rh], 1);
                    if (pos < CAP) win[(rh << 6) + pos] = c;
                }
            }
        }
    } else {
        // catastrophic fallback (never triggers): full edge rescan
        for (int i = tid; i < n_edges; i += 256) {
            int r = idx[i];
            if ((r >> PSHIFT) == p && (((r >> 7) & 1) == half)) {
                int rh = r & 127;
                int c  = idx[n_edges + i];
                int pos = atomicAdd(&cnt2[rh], 1);
                if (pos < CAP) win[(rh << 6) + pos] = c;
            }
        }
    }
    __syncthreads();

    int r0 = (p << PSHIFT) + (half << 7);
    int rows = n_nodes - r0;
    if (rows > RPP / 2) rows = RPP / 2;
    if (rows > 0) {
        int nint4 = rows * (CAP / 4);
        int4* dst = (int4*)(bucket + (long long)r0 * CAP);
        const int4* src = (const int4*)win;
        for (int i = tid; i < nint4; i += 256) dst[i] = src[i];
        if (tid < rows) count[r0 + tid] = cnt2[tid];
    }
}

// ---------------- fallback build: direct scatter ----------------
__global__ void bucket_scatter_kernel(const int* __restrict__ idx,
                                      int* __restrict__ count,
                                      int* __restrict__ bucket, int n_edges) {
    int t = blockIdx.x * blockDim.x + threadIdx.x;
    if (t < n_edges) {
        int r = idx[t];
        int c = idx[n_edges + t];
        int p = atomicAdd(&count[r], 1);
        if (p < CAP) bucket[(long long)r * CAP + p] = c;
    }
}

// ---------------- row kernel, fp16 gathers (v8-identical) ----------------
__global__ void row16_kernel(const float* __restrict__ q,
                             const __half* __restrict__ k16,
                             const __half* __restrict__ v16,
                             const float* __restrict__ eigs,
                             const __half* __restrict__ e16,
                             const float* __restrict__ lambda0,
                             const int* __restrict__ counts,
                             const int* __restrict__ col,
                             const float* __restrict__ kf,
                             const float* __restrict__ vf,
                             const int* __restrict__ idx, int n_edges,
                             float* __restrict__ out, int n_nodes) {
    long long tid = (long long)blockIdx.x * blockDim.x + threadIdx.x;
    int r = (int)(tid >> 6);
    if (r >= n_nodes) return;
    int lane = threadIdx.x & 63;
    int sub = lane & 15;
    int grp = lane >> 4;

    int deg = counts[r];
    const float expL = __expf(lambda0[0]);

    if (deg > CAP) {
        float qs = q[(long long)r * HD + lane] * 0.125f;
        float gs = (lane < ED) ? eigs[(long long)r * ED + lane] * expL : 0.f;
        float accs = 0.f, den = 0.f;
        for (int base = 0; base < n_edges; base += 64) {
            int e = base + lane;
            int rr = (e < n_edges) ? idx[e] : -1;
            int cc = (e < n_edges) ? idx[n_edges + e] : 0;
            unsigned long long mm = __ballot(rr == r);
            while (mm) {
                int b = __ffsll(mm) - 1;
                mm &= mm - 1;
                int c = __shfl(cc, b, 64);
                float kb = kf[(long long)c * HD + lane];
                float gb = (lane < ED) ? eigs[(long long)c * ED + lane] : 0.f;
                float s = qs * kb + gs * gb;
                #pragma unroll
                for (int off = 32; off > 0; off >>= 1) s += __shfl_xor(s, off, 64);
                float e1 = fminf(__expf(s), 5.0f);
                den += e1;
                accs += e1 * vf[(long long)c * HD + lane];
            }
        }
        float inv = (den == 0.f) ? 1.f : __frcp_rn(den);
        out[(long long)r * HD + lane] = accs * inv;
        return;
    }

    long long start = (long long)r * CAP;

    float4 qa = *(const float4*)(q    + (long long)r * HD + sub * 4);
    float2 ga = *(const float2*)(eigs + (long long)r * ED + sub * 2);
    qa.x *= 0.125f; qa.y *= 0.125f; qa.z *= 0.125f; qa.w *= 0.125f;
    ga.x *= expL;   ga.y *= expL;

    float4 acc = make_float4(0.f, 0.f, 0.f, 0.f);
    float den = 0.f;

    for (int base = 0; base < deg; base += 64) {
        int m = deg - base; if (m > 64) m = 64;
        int cl = (lane < m) ? col[start + base + lane] : 0;
        for (int j = 0; j < m; j += 16) {
            int c1 = __shfl(cl, j + grp,      64);
            int c2 = __shfl(cl, j + 4 + grp,  64);
            int c3 = __shfl(cl, j + 8 + grp,  64);
            int c4 = __shfl(cl, j + 12 + grp, 64);
            h4 kb1 = *(const h4*)(k16 + (long long)c1 * HD + sub * 4);
            __half2 gh1 = *(const __half2*)(e16 + (long long)c1 * ED + sub * 2);
            h4 vv1 = *(const h4*)(v16 + (long long)c1 * HD + sub * 4);
            h4 kb2 = *(const h4*)(k16 + (long long)c2 * HD + sub * 4);
            __half2 gh2 = *(const __half2*)(e16 + (long long)c2 * ED + sub * 2);
            h4 vv2 = *(const h4*)(v16 + (long long)c2 * HD + sub * 4);
            h4 kb3 = *(const h4*)(k16 + (long long)c3 * HD + sub * 4);
            __half2 gh3 = *(const __half2*)(e16 + (long long)c3 * ED + sub * 2);
            h4 vv3 = *(const h4*)(v16 + (long long)c3 * HD + sub * 4);
            h4 kb4 = *(const h4*)(k16 + (long long)c4 * HD + sub * 4);
            __half2 gh4 = *(const __half2*)(e16 + (long long)c4 * ED + sub * 2);
            h4 vv4 = *(const h4*)(v16 + (long long)c4 * HD + sub * 4);

            float s1 = qa.x*__low2float(kb1.a) + qa.y*__high2float(kb1.a)
                     + qa.z*__low2float(kb1.b) + qa.w*__high2float(kb1.b)
                     + ga.x*__low2float(gh1)   + ga.y*__high2float(gh1);
            float s2 = qa.x*__low2float(kb2.a) + qa.y*__high2float(kb2.a)
                     + qa.z*__low2float(kb2.b) + qa.w*__high2float(kb2.b)
                     + ga.x*__low2float(gh2)   + ga.y*__high2float(gh2);
            float s3 = qa.x*__low2float(kb3.a) + qa.y*__high2float(kb3.a)
                     + qa.z*__low2float(kb3.b) + qa.w*__high2float(kb3.b)
                     + ga.x*__low2float(gh3)   + ga.y*__high2float(gh3);
            float s4 = qa.x*__low2float(kb4.a) + qa.y*__high2float(kb4.a)
                     + qa.z*__low2float(kb4.b) + qa.w*__high2float(kb4.b)
                     + ga.x*__low2float(gh4)   + ga.y*__high2float(gh4);
            #pragma unroll
            for (int off = 8; off > 0; off >>= 1) {
                s1 += __shfl_xor(s1, off, 64);
                s2 += __shfl_xor(s2, off, 64);
                s3 += __shfl_xor(s3, off, 64);
                s4 += __shfl_xor(s4, off, 64);
            }
            float e1 = fminf(__expf(s1), 5.0f);
            float e2 = fminf(__expf(s2), 5.0f);
            float e3 = fminf(__expf(s3), 5.0f);
            float e4 = fminf(__expf(s4), 5.0f);

            if (j + grp < m) {
                den += e1;
                acc.x += e1 * __low2float(vv1.a); acc.y += e1 * __high2float(vv1.a);
                acc.z += e1 * __low2float(vv1.b); acc.w += e1 * __high2float(vv1.b);
            }
            if (j + 4 + grp < m) {
                den += e2;
                acc.x += e2 * __low2float(vv2.a); acc.y += e2 * __high2float(vv2.a);
                acc.z += e2 * __low2float(vv2.b); acc.w += e2 * __high2float(vv2.b);
            }
            if (j + 8 + grp < m) {
                den += e3;
                acc.x += e3 * __low2float(vv3.a); acc.y += e3 * __high2float(vv3.a);
                acc.z += e3 * __low2float(vv3.b); acc.w += e3 * __high2float(vv3.b);
            }
            if (j + 12 + grp < m) {
                den += e4;
                acc.x += e4 * __low2float(vv4.a); acc.y += e4 * __high2float(vv4.a);
                acc.z += e4 * __low2float(vv4.b); acc.w += e4 * __high2float(vv4.b);
            }
        }
    }

    #pragma unroll
    for (int off = 16; off < 64; off <<= 1) {
        acc.x += __shfl_xor(acc.x, off, 64);
        acc.y += __shfl_xor(acc.y, off, 64);
        acc.z += __shfl_xor(acc.z, off, 64);
        acc.w += __shfl_xor(acc.w, off, 64);
        den   += __shfl_xor(den,   off, 64);
    }

    if (grp == 0) {
        float inv = (den == 0.0f) ? 1.0f : __frcp_rn(den);
        float4 o = make_float4(acc.x * inv, acc.y * inv, acc.z * inv, acc.w * inv);
        *(float4*)(out + (long long)r * HD + sub * 4) = o;
    }
}

// ---------------- row kernel, fp32 (fallback tiers) ----------------
__global__ void row_kernel(const float* __restrict__ q, const float* __restrict__ k,
                           const float* __restrict__ v, const float* __restrict__ eigs,
                           const float* __restrict__ lambda0,
                           const int* __restrict__ counts,
                           const int* __restrict__ col,
                           const int* __restrict__ idx, int n_edges,
                           float* __restrict__ out, int n_nodes) {
    long long tid = (long long)blockIdx.x * blockDim.x + threadIdx.x;
    int r = (int)(tid >> 6);
    if (r >= n_nodes) return;
    int lane = threadIdx.x & 63;
    int sub = lane & 15;
    int grp = lane >> 4;

    int deg = counts[r];
    const float expL = __expf(lambda0[0]);

    if (deg > CAP) {
        float qs = q[(long long)r * HD + lane] * 0.125f;
        float gs = (lane < ED) ? eigs[(long long)r * ED + lane] * expL : 0.f;
        float accs = 0.f, den = 0.f;
        for (int base = 0; base < n_edges; base += 64) {
            int e = base + lane;
            int rr = (e < n_edges) ? idx[e] : -1;
            int cc = (e < n_edges) ? idx[n_edges + e] : 0;
            unsigned long long mm = __ballot(rr == r);
            while (mm) {
                int b = __ffsll(mm) - 1;
                mm &= mm - 1;
                int c = __shfl(cc, b, 64);
                float kb = k[(long long)c * HD + lane];
                float gb = (lane < ED) ? eigs[(long long)c * ED + lane] : 0.f;
                float s = qs * kb + gs * gb;
                #pragma unroll
                for (int off = 32; off > 0; off >>= 1) s += __shfl_xor(s, off, 64);
                float e1 = fminf(__expf(s), 5.0f);
                den += e1;
                accs += e1 * v[(long long)c * HD + lane];
            }
        }
        float inv = (den == 0.f) ? 1.f : __frcp_rn(den);
        out[(long long)r * HD + lane] = accs * inv;
        return;
    }

    long long start = (long long)r * CAP;

    float4 qa = *(const float4*)(q    + (long long)r * HD + sub * 4);
    float2 ga = *(const float2*)(eigs + (long long)r * ED + sub * 2);
    qa.x *= 0.125f; qa.y *= 0.125f; qa.z *= 0.125f; qa.w *= 0.125f;
    ga.x *= expL;   ga.y *= expL;

    float4 acc = make_float4(0.f, 0.f, 0.f, 0.f);
    float den = 0.f;

    for (int base = 0; base < deg; base += 64) {
        int m = deg - base; if (m > 64) m = 64;
        int cl = (lane < m) ? col[start + base + lane] : 0;
        for (int j = 0; j < m; j += 8) {
            int c1 = __shfl(cl, j + grp,     64);
            int c2 = __shfl(cl, j + 4 + grp, 64);
            float4 kb1 = *(const float4*)(k    + (long long)c1 * HD + sub * 4);
            float2 gb1 = *(const float2*)(eigs + (long long)c1 * ED + sub * 2);
            float4 vv1 = *(const float4*)(v    + (long long)c1 * HD + sub * 4);
            float4 kb2 = *(const float4*)(k    + (long long)c2 * HD + sub * 4);
            float2 gb2 = *(const float2*)(eigs + (long long)c2 * ED + sub * 2);
            float4 vv2 = *(const float4*)(v    + (long long)c2 * HD + sub * 4);

            float s1 = qa.x*kb1.x + qa.y*kb1.y + qa.z*kb1.z + qa.w*kb1.w
                     + ga.x*gb1.x + ga.y*gb1.y;
            float s2 = qa.x*kb2.x + qa.y*kb2.y + qa.z*kb2.z + qa.w*kb2.w
                     + ga.x*gb2.x + ga.y*gb2.y;
            #pragma unroll
            for (int off = 8; off > 0; off >>= 1) {
                s1 += __shfl_xor(s1, off, 64);
                s2 += __shfl_xor(s2, off, 64);
            }
            float e1 = fminf(__expf(s1), 5.0f);
            float e2 = fminf(__expf(s2), 5.0f);

            if (j + grp < m) {
                den += e1;
                acc.x += e1 * vv1.x; acc.y += e1 * vv1.y;
                acc.z += e1 * vv1.z; acc.w += e1 * vv1.w;
            }
            if (j + 4 + grp < m) {
                den += e2;
                acc.x += e2 * vv2.x; acc.y += e2 * vv2.y;
                acc.z += e2 * vv2.z; acc.w += e2 * vv2.w;
            }
        }
    }

    #pragma unroll
    for (int off = 16; off < 64; off <<= 1) {
        acc.x += __shfl_xor(acc.x, off, 64);
        acc.y += __shfl_xor(acc.y, off, 64);
        acc.z += __shfl_xor(acc.z, off, 64);
        acc.w += __shfl_xor(acc.w, off, 64);
        den   += __shfl_xor(den,   off, 64);
    }

    if (grp == 0) {
        float inv = (den == 0.0f) ? 1.0f : __frcp_rn(den);
        float4 o = make_float4(acc.x * inv, acc.y * inv, acc.z * inv, acc.w * inv);
        *(float4*)(out + (long long)r * HD + sub * 4) = o;
    }
}

// ---------------- tier-3: fused atomic path ----------------
__global__ void edge_fused_kernel(const float* __restrict__ q,
                                  const float* __restrict__ k,
                                  const float* __restrict__ v,
                                  const float* __restrict__ eigs,
                                  const float* __restrict__ lambda0,
                                  const int* __restrict__ idx,
                                  float* __restrict__ denom,
                                  float* __restrict__ out, int n_edges) {
    long long gid = (long long)blockIdx.x * blockDim.x + threadIdx.x;
    int lane = threadIdx.x & 63;
    int edge = (int)(gid >> 4);
    int sub  = (int)(gid & 15);
    int valid = (edge < n_edges);
    int ec = valid ? edge : (n_edges - 1);
    int i0 = idx[ec];
    int i1 = idx[n_edges + ec];
    const float expL = __expf(lambda0[0]);
    float4 qa = *(const float4*)(q + (long long)i0 * HD + sub * 4);
    float4 kb = *(const float4*)(k + (long long)i1 * HD + sub * 4);
    float c = (qa.x*kb.x + qa.y*kb.y + qa.z*kb.z + qa.w*kb.w) * 0.125f;
    float2 ea = *(const float2*)(eigs + (long long)i0 * ED + sub * 2);
    float2 eb = *(const float2*)(eigs + (long long)i1 * ED + sub * 2);
    c += expL * (ea.x * eb.x + ea.y * eb.y);
    #pragma unroll
    for (int off = 8; off > 0; off >>= 1) c += __shfl_xor(c, off, 64);
    float e = fminf(__expf(c), 5.0f);
    if (valid && sub == 0) atomicAdd(&denom[i0], e);
    #pragma unroll
    for (int j = 0; j < 4; ++j) {
        float ej = __shfl(e,     j * 16, 64);
        int   r  = __shfl(i0,    j * 16, 64);
        int   s  = __shfl(i1,    j * 16, 64);
        int   vj = __shfl(valid, j * 16, 64);
        if (vj) {
            float vv = v[(long long)s * HD + lane];
            atomicAdd(&out[(long long)r * HD + lane], ej * vv);
        }
    }
}

__global__ void normalize_kernel(float* __restrict__ out,
                                 const float* __restrict__ denom, int n_nodes) {
    int t = blockIdx.x * blockDim.x + threadIdx.x;
    int total = n_nodes * (HD / 4);
    if (t >= total) return;
    int row = t >> 4;
    float d = denom[row];
    float inv = (d == 0.0f) ? 1.0f : __frcp_rn(d);
    float4* o4 = (float4*)out;
    float4 x = o4[t];
    x.x *= inv; x.y *= inv; x.z *= inv; x.w *= inv;
    o4[t] = x;
}

extern "C" void kernel_launch(void* const* d_in, const int* in_sizes, int n_in,
                              void* d_out, int out_size, void* d_ws, size_t ws_size,
                              hipStream_t stream) {
    const float* q       = (const float*)d_in[0];
    const float* k       = (const float*)d_in[1];
    const float* v       = (const float*)d_in[2];
    const float* eigs    = (const float*)d_in[3];
    const float* lambda0 = (const float*)d_in[4];
    const int*   idx     = (const int*)d_in[5];   // [2, E], int32

    const int n_edges = in_sizes[5] / 2;
    const int n_nodes = in_sizes[0] / HD;

    const int NP = (n_nodes + RPP - 1) / RPP;
    const int eb = (n_edges + 255) / 256;
    long long rthreads = (long long)n_nodes * 64;
    const int rb = (int)((rthreads + 255) / 256);

    size_t smbytes = (size_t)NP * (1 + D1) * sizeof(int);
    bool geom_ok = (smbytes <= 60 * 1024) && (n_nodes <= 0x1FFFF);

    size_t h16 = (size_t)n_nodes * (HD + HD + ED) * sizeof(__half);
    size_t fixed = (size_t)n_nodes * sizeof(int)
                 + (size_t)n_nodes * CAP * sizeof(int);
    size_t pbytes = (size_t)NP * (size_t)NBIN * SLICE * sizeof(int);
    size_t hdrb = (size_t)NBIN * sizeof(int);
    size_t spb  = (size_t)NBIN * SPCAP_B * sizeof(long long);
    size_t n16 = h16 + fixed + pbytes + hdrb + spb + 16;   // ~73MB
    size_t n32 = fixed + pbytes + hdrb + spb + 16;         // ~41MB
    size_t need2 = fixed;

    long long pcap = (long long)NBIN * SLICE;
    int chunk = (n_edges + NBIN - 1) / NBIN;

    if (geom_ok && ws_size >= n16) {
        // -------- tier 1: 3-dispatch fp16 path, no memset --------
        char* base = (char*)d_ws;
        __half* k16 = (__half*)base;                     // [N*HD]
        __half* v16 = k16 + (size_t)n_nodes * HD;        // [N*HD]
        __half* e16 = v16 + (size_t)n_nodes * HD;        // [N*ED]
        int* count  = (int*)(e16 + (size_t)n_nodes * ED);// [N]
        int* bucket = count + n_nodes;                   // [N*CAP]
        int* part   = bucket + (size_t)n_nodes * CAP;    // [NP*NBIN*SLICE]
        int* sphdr  = part + (size_t)NP * pcap;          // [NBIN]
        size_t soff = (size_t)((char*)(sphdr + NBIN) - base);
        soff = (soff + 7) & ~(size_t)7;
        long long* spill = (long long*)(base + soff);    // [NBIN*SPCAP_B]

        p1_wide_kernel<<<2 * NBIN, 256, smbytes, stream>>>(
            idx, n_edges, NP, chunk, pcap, part, spill, sphdr,
            k, v, eigs, k16, v16, e16,
            (long long)n_nodes * HD / 4, (long long)n_nodes * ED / 4);
        p2_bucket_kernel<<<2 * NP, 256, 0, stream>>>(
            part, spill, sphdr, idx, n_edges, count, bucket, n_nodes, pcap);
        row16_kernel<<<rb, 256, 0, stream>>>(q, k16, v16, eigs, e16, lambda0,
                                             count, bucket, k, v, idx, n_edges,
                                             (float*)d_out, n_nodes);
    } else if (geom_ok && ws_size >= n32) {
        // -------- tier 1f: 3-dispatch fp32 path --------
        char* base = (char*)d_ws;
        int* count  = (int*)base;
        int* bucket = count + n_nodes;
        int* part   = bucket + (size_t)n_nodes * CAP;
        int* sphdr  = part + (size_t)NP * pcap;
        size_t soff = (size_t)((char*)(sphdr + NBIN) - base);
        soff = (soff + 7) & ~(size_t)7;
        long long* spill = (long long*)(base + soff);

        p1_wide_kernel<<<2 * NBIN, 256, smbytes, stream>>>(
            idx, n_edges, NP, chunk, pcap, part, spill, sphdr,
            nullptr, nullptr, nullptr, nullptr, nullptr, nullptr, 0, 0);
        p2_bucket_kernel<<<2 * NP, 256, 0, stream>>>(
            part, spill, sphdr, idx, n_edges, count, bucket, n_nodes, pcap);
        row_kernel<<<rb, 256, 0, stream>>>(q, k, v, eigs, lambda0, count, bucket,
                                           idx, n_edges, (float*)d_out, n_nodes);
    } else if (ws_size >= need2) {
        // -------- tier 2: direct scatter --------
        int* count  = (int*)d_ws;
        int* bucket = count + n_nodes;
        hipMemsetAsync(count, 0, (size_t)n_nodes * sizeof(int), stream);
        bucket_scatter_kernel<<<eb, 256, 0, stream>>>(idx, count, bucket, n_edges);
        row_kernel<<<rb, 256, 0, stream>>>(q, k, v, eigs, lambda0, count, bucket,
                                           idx, n_edges, (float*)d_out, n_nodes);
    } else {
        // -------- tier 3: fused atomic path --------
        float* denom = (float*)d_ws;   // [N]
        hipMemsetAsync(denom, 0, (size_t)n_nodes * sizeof(float), stream);
        hipMemsetAsync(d_out, 0, (size_t)out_size * sizeof(float), stream);
        long long threads = (long long)n_edges * 16;
        int grid = (int)((threads + 255) / 256);
        edge_fused_kernel<<<grid, 256, 0, stream>>>(q, k, v, eigs, lambda0, idx,
                                                    denom, (float*)d_out, n_edges);
        int n4 = n_nodes * (HD / 4);
        normalize_kernel<<<(n4 + 255) / 256, 256, 0, stream>>>((float*)d_out,
                                                               denom, n_nodes);
    }
}